// Round 10
// baseline (87.778 us; speedup 1.0000x reference)
//
#include <hip/hip_runtime.h>
#include <hip/hip_bf16.h>

#define BATCH 4
#define S_LEN 2048
#define D_MOD 256
#define NH 8
#define HDIM 32
#define QLOG2E 0.09016844f   // (1/16) * log2(e); folded into Q at projection

typedef short bf16x8 __attribute__((ext_vector_type(8)));
typedef short short4v __attribute__((ext_vector_type(4)));
typedef float f32x4 __attribute__((ext_vector_type(4)));

__device__ __forceinline__ short f2bf(float f) {
    __hip_bfloat16 h = __float2bfloat16(f);
    return *reinterpret_cast<short*>(&h);
}

// ---------------------------------------------------------------------------
// K0: W fp32 [k][n] -> WT bf16 [n][k] for Wq,Wk,Wv,Wo.  grid (4, 32).
// ---------------------------------------------------------------------------
__global__ __launch_bounds__(256) void wtrans_kernel(
    const float* __restrict__ Wq, const float* __restrict__ Wk,
    const float* __restrict__ Wv, const float* __restrict__ Wo,
    short* __restrict__ WT)
{
    const int wsel = blockIdx.x;
    const int k0 = blockIdx.y * 8;
    const float* W = wsel == 0 ? Wq : (wsel == 1 ? Wk : (wsel == 2 ? Wv : Wo));
    short* T = WT + (size_t)wsel * 256 * 256;
    int n = threadIdx.x;
    bf16x8 o;
    #pragma unroll
    for (int kk = 0; kk < 8; ++kk)
        o[kk] = f2bf(W[(size_t)(k0 + kk) * 256 + n]);
    *(bf16x8*)&T[(size_t)n * 256 + k0] = o;
}

// ---------------------------------------------------------------------------
// K1: QKV projection (Q pre-scaled by QLOG2E).  Q,K packed [bh][s][32];
// V transposed [bh][hd][s].  grid (256, 3).
// ---------------------------------------------------------------------------
__global__ __launch_bounds__(256) void qkv_proj_kernel(
    const float* __restrict__ q_in, const float* __restrict__ k_in,
    const float* __restrict__ v_in, const short* __restrict__ WT,
    const float* __restrict__ bq, const float* __restrict__ bk,
    const float* __restrict__ bv,
    short* __restrict__ Qp, short* __restrict__ Kp, short* __restrict__ Vt)
{
    __shared__ short lsA[32][264];
    const int mt = blockIdx.x;
    const int seg = blockIdx.y;
    const float* A = seg == 0 ? q_in : (seg == 1 ? k_in : v_in);
    const short* WTs = WT + (size_t)seg * 65536;
    const float* bias = seg == 0 ? bq : (seg == 1 ? bk : bv);
    const int m0 = mt * 32;
    const int tid = threadIdx.x;

    {
        const float4* A4 = (const float4*)(A + (size_t)m0 * D_MOD);
        #pragma unroll
        for (int i = 0; i < 8; ++i) {
            int f4 = tid + i * 256;
            int row = f4 >> 6, c4 = f4 & 63;
            float4 v = A4[f4];
            short4v o;
            o.x = f2bf(v.x); o.y = f2bf(v.y); o.z = f2bf(v.z); o.w = f2bf(v.w);
            *(short4v*)&lsA[row][c4 * 4] = o;
        }
    }
    __syncthreads();

    const int w = tid >> 6, l = tid & 63, g = l >> 4, r15 = l & 15;
    bf16x8 af[2][8];
    #pragma unroll
    for (int f = 0; f < 2; ++f)
        #pragma unroll
        for (int kk = 0; kk < 8; ++kk)
            af[f][kk] = *(const bf16x8*)&lsA[f * 16 + r15][kk * 32 + 8 * g];

    const int bidx = m0 >> 11;
    const int s_base = m0 & (S_LEN - 1);

    #pragma unroll
    for (int ntl = 0; ntl < 4; ++ntl) {
        int col = w * 64 + ntl * 16 + r15;
        f32x4 acc0 = {}, acc1 = {};
        #pragma unroll
        for (int kk = 0; kk < 8; ++kk) {
            bf16x8 b = *(const bf16x8*)&WTs[(size_t)col * 256 + kk * 32 + 8 * g];
            acc0 = __builtin_amdgcn_mfma_f32_16x16x32_bf16(af[0][kk], b, acc0, 0, 0, 0);
            acc1 = __builtin_amdgcn_mfma_f32_16x16x32_bf16(af[1][kk], b, acc1, 0, 0, 0);
        }
        float bval = bias[col];
        int h = col >> 5, hd = col & 31;
        if (seg == 0) {
            short* Outh = Qp + ((size_t)(bidx * NH + h) * S_LEN) * HDIM;
            #pragma unroll
            for (int r = 0; r < 4; ++r) {
                int s0 = s_base + 4 * g + r;
                Outh[(size_t)s0 * HDIM + hd]        = f2bf((acc0[r] + bval) * QLOG2E);
                Outh[(size_t)(s0 + 16) * HDIM + hd] = f2bf((acc1[r] + bval) * QLOG2E);
            }
        } else if (seg == 1) {
            short* Outh = Kp + ((size_t)(bidx * NH + h) * S_LEN) * HDIM;
            #pragma unroll
            for (int r = 0; r < 4; ++r) {
                int s0 = s_base + 4 * g + r;
                Outh[(size_t)s0 * HDIM + hd]        = f2bf(acc0[r] + bval);
                Outh[(size_t)(s0 + 16) * HDIM + hd] = f2bf(acc1[r] + bval);
            }
        } else {
            short* Vh = Vt + ((size_t)(bidx * NH + h) * HDIM + hd) * S_LEN;
            short4v o0, o1;
            #pragma unroll
            for (int r = 0; r < 4; ++r) { o0[r] = f2bf(acc0[r] + bval); o1[r] = f2bf(acc1[r] + bval); }
            size_t s = s_base + 4 * g;
            *(short4v*)&Vh[s]      = o0;
            *(short4v*)&Vh[s + 16] = o1;
        }
    }
}

// ---------------------------------------------------------------------------
// K2: causal attention, REGISTER-ONLY P (swapped QK^T + permuted-k PV).
// S^T = mfma(K, Q): lane (g,r15) holds P[q=r15][keys 16n+4g+r] -- lane-local q.
// PV uses k-permutation kappa(g,j) = 16*(2ks + (j>>2)) + 4g + (j&3) on BOTH
// operands: A-frag = lane's own packed P regs; B-frag = two 8B V^T loads.
// No LDS in the main loop; LDS only for the 4-wave key-split combine.
// grid 2048 (block = 4 waves key-split over one (bh, 32 q-rows)).
// ---------------------------------------------------------------------------
__global__ __launch_bounds__(256) void attn_kernel(
    const short* __restrict__ Qp, const short* __restrict__ Kp,
    const short* __restrict__ Vt, short* __restrict__ Ab)
{
    __shared__ float comb[4][32][36];
    __shared__ float psl[4][2][16];

    const int idx = blockIdx.x;
    const int bh = 4 * (idx & 7) + ((idx >> 3) & 3);   // XCD-local bh groups
    const int jq = 63 - (idx >> 5);                    // heavy-first
    const int b = bh >> 3, hh = bh & 7;
    const int tid = threadIdx.x;
    const int w = tid >> 6, l = tid & 63, g = l >> 4, r15 = l & 15;
    const int q0 = jq * 32;

    const short* Qph = Qp + (size_t)bh * S_LEN * HDIM;
    const short* Kph = Kp + (size_t)bh * S_LEN * HDIM;
    const short* Vtp = Vt + (size_t)bh * HDIM * S_LEN;

    // Q B-fragments (q rows q0..q0+15 and q0+16..q0+31)
    bf16x8 aq0 = *(const bf16x8*)&Qph[(q0 + r15) * HDIM + 8 * g];
    bf16x8 aq1 = *(const bf16x8*)&Qph[(q0 + 16 + r15) * HDIM + 8 * g];

    f32x4 o00 = {}, o01 = {}, o10 = {}, o11 = {};   // [h][n2]
    float ps0 = 0.f, ps1 = 0.f;                     // rowsum for q=q0+r15 / +16
    const f32x4 zero = {};
    const int ntiles = (q0 + 95) >> 6;

    const short* kp  = Kph + w * 2048 + r15 * 32 + 8 * g;     // K[s=k0+n16+r15][8g..]
    const short* vp0 = Vtp + r15 * S_LEN + w * 64 + 4 * g;    // V^T[hd=r15][s=k0+4g..]
    const short* vp1 = vp0 + 16 * S_LEN;                      // hd = 16+r15

    for (int kt = w; kt < ntiles; kt += 4, kp += 8192, vp0 += 256, vp1 += 256) {
        const int k0 = kt * 64;
        const bool full = (k0 + 63) <= q0;

        // V loads early (independent of QK): s = k0 + 32ks + {0,16} + 4g..+3
        short4v v000 = *(const short4v*)(vp0);
        short4v v001 = *(const short4v*)(vp0 + 16);
        short4v v010 = *(const short4v*)(vp1);
        short4v v011 = *(const short4v*)(vp1 + 16);
        short4v v100 = *(const short4v*)(vp0 + 32);
        short4v v101 = *(const short4v*)(vp0 + 48);
        short4v v110 = *(const short4v*)(vp1 + 32);
        short4v v111 = *(const short4v*)(vp1 + 48);

        // Swapped QK^T: lane gets S[q=r15(+16h)][key=k0+16n+4g+r]
        short4v pb[4][2];
        #pragma unroll
        for (int n = 0; n < 4; ++n) {
            bf16x8 ak = *(const bf16x8*)(kp + n * 512);
            __builtin_amdgcn_s_setprio(1);
            f32x4 s0 = __builtin_amdgcn_mfma_f32_16x16x32_bf16(ak, aq0, zero, 0, 0, 0);
            f32x4 s1 = __builtin_amdgcn_mfma_f32_16x16x32_bf16(ak, aq1, zero, 0, 0, 0);
            __builtin_amdgcn_s_setprio(0);
            if (full) {
                #pragma unroll
                for (int r = 0; r < 4; ++r) {
                    float e0 = exp2f(s0[r]);
                    float e1 = exp2f(s1[r]);
                    ps0 += e0; ps1 += e1;
                    pb[n][0][r] = f2bf(e0);
                    pb[n][1][r] = f2bf(e1);
                }
            } else {
                const int kb = k0 + n * 16 + 4 * g;
                #pragma unroll
                for (int r = 0; r < 4; ++r) {
                    int key = kb + r;
                    float e0 = (key <= q0 + r15)      ? exp2f(s0[r]) : 0.0f;
                    float e1 = (key <= q0 + 16 + r15) ? exp2f(s1[r]) : 0.0f;
                    ps0 += e0; ps1 += e1;
                    pb[n][0][r] = f2bf(e0);
                    pb[n][1][r] = f2bf(e1);
                }
            }
        }

        // PV with permuted k: A-frag = own P regs, B-frag = matching V order
        bf16x8 pa00 = __builtin_shufflevector(pb[0][0], pb[1][0], 0,1,2,3,4,5,6,7);
        bf16x8 pa01 = __builtin_shufflevector(pb[0][1], pb[1][1], 0,1,2,3,4,5,6,7);
        bf16x8 pa10 = __builtin_shufflevector(pb[2][0], pb[3][0], 0,1,2,3,4,5,6,7);
        bf16x8 pa11 = __builtin_shufflevector(pb[2][1], pb[3][1], 0,1,2,3,4,5,6,7);
        bf16x8 bv00 = __builtin_shufflevector(v000, v001, 0,1,2,3,4,5,6,7);
        bf16x8 bv01 = __builtin_shufflevector(v010, v011, 0,1,2,3,4,5,6,7);
        bf16x8 bv10 = __builtin_shufflevector(v100, v101, 0,1,2,3,4,5,6,7);
        bf16x8 bv11 = __builtin_shufflevector(v110, v111, 0,1,2,3,4,5,6,7);

        __builtin_amdgcn_s_setprio(1);
        o00 = __builtin_amdgcn_mfma_f32_16x16x32_bf16(pa00, bv00, o00, 0, 0, 0);
        o01 = __builtin_amdgcn_mfma_f32_16x16x32_bf16(pa00, bv01, o01, 0, 0, 0);
        o10 = __builtin_amdgcn_mfma_f32_16x16x32_bf16(pa01, bv00, o10, 0, 0, 0);
        o11 = __builtin_amdgcn_mfma_f32_16x16x32_bf16(pa01, bv01, o11, 0, 0, 0);
        o00 = __builtin_amdgcn_mfma_f32_16x16x32_bf16(pa10, bv10, o00, 0, 0, 0);
        o01 = __builtin_amdgcn_mfma_f32_16x16x32_bf16(pa10, bv11, o01, 0, 0, 0);
        o10 = __builtin_amdgcn_mfma_f32_16x16x32_bf16(pa11, bv10, o10, 0, 0, 0);
        o11 = __builtin_amdgcn_mfma_f32_16x16x32_bf16(pa11, bv11, o11, 0, 0, 0);
        __builtin_amdgcn_s_setprio(0);
    }

    // rowsum: reduce across the 4 groups (lane ^16, ^32)
    ps0 += __shfl_xor(ps0, 16); ps0 += __shfl_xor(ps0, 32);
    ps1 += __shfl_xor(ps1, 16); ps1 += __shfl_xor(ps1, 32);

    // combine across key-split waves via LDS
    if (l < 16) { psl[w][0][l] = ps0; psl[w][1][l] = ps1; }
    #pragma unroll
    for (int r = 0; r < 4; ++r) {
        comb[w][4 * g + r][r15]           = o00[r];
        comb[w][4 * g + r][16 + r15]      = o01[r];
        comb[w][16 + 4 * g + r][r15]      = o10[r];
        comb[w][16 + 4 * g + r][16 + r15] = o11[r];
    }
    __syncthreads();

    // epilogue: 256 threads cover 32 q-rows x 32 hd (4 each)
    {
        int q = tid >> 3, hd0 = (tid & 7) * 4;
        float ps = psl[0][q >> 4][q & 15] + psl[1][q >> 4][q & 15]
                 + psl[2][q >> 4][q & 15] + psl[3][q >> 4][q & 15];
        float inv = __fdividef(1.0f, ps);
        short4v o;
        #pragma unroll
        for (int j = 0; j < 4; ++j) {
            float v = comb[0][q][hd0 + j] + comb[1][q][hd0 + j]
                    + comb[2][q][hd0 + j] + comb[3][q][hd0 + j];
            o[j] = f2bf(v * inv);
        }
        *(short4v*)&Ab[((size_t)b * S_LEN + q0 + q) * D_MOD + hh * HDIM + hd0] = o;
    }
}

// ---------------------------------------------------------------------------
// K3: output projection, streaming (no LDS).  grid 256.
// ---------------------------------------------------------------------------
__global__ __launch_bounds__(256) void out_proj_kernel(
    const short* __restrict__ Ab, const short* __restrict__ WTo,
    const float* __restrict__ bo, float* __restrict__ out)
{
    const int m0 = blockIdx.x * 32;
    const int tid = threadIdx.x;
    const int w = tid >> 6, l = tid & 63, g = l >> 4, r15 = l & 15;

    bf16x8 af[2][8];
    #pragma unroll
    for (int f = 0; f < 2; ++f)
        #pragma unroll
        for (int kk = 0; kk < 8; ++kk)
            af[f][kk] = *(const bf16x8*)&Ab[(size_t)(m0 + f * 16 + r15) * D_MOD + kk * 32 + 8 * g];

    #pragma unroll
    for (int ntl = 0; ntl < 4; ++ntl) {
        int col = w * 64 + ntl * 16 + r15;
        f32x4 acc0 = {}, acc1 = {};
        #pragma unroll
        for (int kk = 0; kk < 8; ++kk) {
            bf16x8 bfr = *(const bf16x8*)&WTo[(size_t)col * 256 + kk * 32 + 8 * g];
            acc0 = __builtin_amdgcn_mfma_f32_16x16x32_bf16(af[0][kk], bfr, acc0, 0, 0, 0);
            acc1 = __builtin_amdgcn_mfma_f32_16x16x32_bf16(af[1][kk], bfr, acc1, 0, 0, 0);
        }
        float bval = bo[col];
        #pragma unroll
        for (int r = 0; r < 4; ++r) {
            out[(size_t)(m0 + 4 * g + r) * D_MOD + col]      = acc0[r] + bval;
            out[(size_t)(m0 + 16 + 4 * g + r) * D_MOD + col] = acc1[r] + bval;
        }
    }
}

extern "C" void kernel_launch(void* const* d_in, const int* in_sizes, int n_in,
                              void* d_out, int out_size, void* d_ws, size_t ws_size,
                              hipStream_t stream) {
    const float* q_in = (const float*)d_in[0];
    const float* k_in = (const float*)d_in[1];
    const float* v_in = (const float*)d_in[2];
    // d_in[3] = mask: causal tril, applied analytically.
    const float* Wq = (const float*)d_in[4];
    const float* bq = (const float*)d_in[5];
    const float* Wk = (const float*)d_in[6];
    const float* bk = (const float*)d_in[7];
    const float* Wv = (const float*)d_in[8];
    const float* bv = (const float*)d_in[9];
    const float* Wo = (const float*)d_in[10];
    const float* bo = (const float*)d_in[11];
    float* out = (float*)d_out;

    const size_t NTOK = (size_t)BATCH * S_LEN * D_MOD;  // 2M elements
    short* WT = (short*)d_ws;           // 4 x 256 x 256 bf16 = 512 KB
    short* Qp = WT + 4 * 65536;         // packed [bh][s][32], pre-scaled
    short* Kp = Qp + NTOK;              // packed [bh][s][32]
    short* Vt = Kp + NTOK;              // transposed [bh][hd][s]
    short* Ab = Vt + NTOK;              // [b][s][256]

    wtrans_kernel<<<dim3(4, 32), 256, 0, stream>>>(Wq, Wk, Wv, Wo, WT);
    qkv_proj_kernel<<<dim3(256, 3), 256, 0, stream>>>(
        q_in, k_in, v_in, WT, bq, bk, bv, Qp, Kp, Vt);
    attn_kernel<<<2048, 256, 0, stream>>>(Qp, Kp, Vt, Ab);
    out_proj_kernel<<<256, 256, 0, stream>>>(Ab, WT + 3 * 65536, bo, out);
}

// Round 11
// 83.365 us; speedup vs baseline: 1.0529x; 1.0529x over previous
//
#include <hip/hip_runtime.h>
#include <hip/hip_bf16.h>

#define BATCH 4
#define S_LEN 2048
#define D_MOD 256
#define NH 8
#define HDIM 32
#define QLOG2E 0.09016844f   // (1/16) * log2(e); folded into Q at projection

typedef short bf16x8 __attribute__((ext_vector_type(8)));
typedef short short4v __attribute__((ext_vector_type(4)));
typedef float f32x4 __attribute__((ext_vector_type(4)));

__device__ __forceinline__ short f2bf(float f) {
    __hip_bfloat16 h = __float2bfloat16(f);
    return *reinterpret_cast<short*>(&h);
}

// ---------------------------------------------------------------------------
// K0: W fp32 [k][n] -> WT bf16 [n][k] for Wq,Wk,Wv,Wo.  grid (4, 32).
// ---------------------------------------------------------------------------
__global__ __launch_bounds__(256) void wtrans_kernel(
    const float* __restrict__ Wq, const float* __restrict__ Wk,
    const float* __restrict__ Wv, const float* __restrict__ Wo,
    short* __restrict__ WT)
{
    const int wsel = blockIdx.x;
    const int k0 = blockIdx.y * 8;
    const float* W = wsel == 0 ? Wq : (wsel == 1 ? Wk : (wsel == 2 ? Wv : Wo));
    short* T = WT + (size_t)wsel * 256 * 256;
    int n = threadIdx.x;
    bf16x8 o;
    #pragma unroll
    for (int kk = 0; kk < 8; ++kk)
        o[kk] = f2bf(W[(size_t)(k0 + kk) * 256 + n]);
    *(bf16x8*)&T[(size_t)n * 256 + k0] = o;
}

// ---------------------------------------------------------------------------
// K1: QKV projection (Q pre-scaled by QLOG2E).  Q,K packed [bh][s][32];
// V transposed [bh][hd][s].  grid (256, 3).
// ---------------------------------------------------------------------------
__global__ __launch_bounds__(256) void qkv_proj_kernel(
    const float* __restrict__ q_in, const float* __restrict__ k_in,
    const float* __restrict__ v_in, const short* __restrict__ WT,
    const float* __restrict__ bq, const float* __restrict__ bk,
    const float* __restrict__ bv,
    short* __restrict__ Qp, short* __restrict__ Kp, short* __restrict__ Vt)
{
    __shared__ short lsA[32][264];
    const int mt = blockIdx.x;
    const int seg = blockIdx.y;
    const float* A = seg == 0 ? q_in : (seg == 1 ? k_in : v_in);
    const short* WTs = WT + (size_t)seg * 65536;
    const float* bias = seg == 0 ? bq : (seg == 1 ? bk : bv);
    const int m0 = mt * 32;
    const int tid = threadIdx.x;

    {
        const float4* A4 = (const float4*)(A + (size_t)m0 * D_MOD);
        #pragma unroll
        for (int i = 0; i < 8; ++i) {
            int f4 = tid + i * 256;
            int row = f4 >> 6, c4 = f4 & 63;
            float4 v = A4[f4];
            short4v o;
            o.x = f2bf(v.x); o.y = f2bf(v.y); o.z = f2bf(v.z); o.w = f2bf(v.w);
            *(short4v*)&lsA[row][c4 * 4] = o;
        }
    }
    __syncthreads();

    const int w = tid >> 6, l = tid & 63, g = l >> 4, r15 = l & 15;
    bf16x8 af[2][8];
    #pragma unroll
    for (int f = 0; f < 2; ++f)
        #pragma unroll
        for (int kk = 0; kk < 8; ++kk)
            af[f][kk] = *(const bf16x8*)&lsA[f * 16 + r15][kk * 32 + 8 * g];

    const int bidx = m0 >> 11;
    const int s_base = m0 & (S_LEN - 1);

    #pragma unroll
    for (int ntl = 0; ntl < 4; ++ntl) {
        int col = w * 64 + ntl * 16 + r15;
        f32x4 acc0 = {}, acc1 = {};
        #pragma unroll
        for (int kk = 0; kk < 8; ++kk) {
            bf16x8 b = *(const bf16x8*)&WTs[(size_t)col * 256 + kk * 32 + 8 * g];
            acc0 = __builtin_amdgcn_mfma_f32_16x16x32_bf16(af[0][kk], b, acc0, 0, 0, 0);
            acc1 = __builtin_amdgcn_mfma_f32_16x16x32_bf16(af[1][kk], b, acc1, 0, 0, 0);
        }
        float bval = bias[col];
        int h = col >> 5, hd = col & 31;
        if (seg == 0) {
            short* Outh = Qp + ((size_t)(bidx * NH + h) * S_LEN) * HDIM;
            #pragma unroll
            for (int r = 0; r < 4; ++r) {
                int s0 = s_base + 4 * g + r;
                Outh[(size_t)s0 * HDIM + hd]        = f2bf((acc0[r] + bval) * QLOG2E);
                Outh[(size_t)(s0 + 16) * HDIM + hd] = f2bf((acc1[r] + bval) * QLOG2E);
            }
        } else if (seg == 1) {
            short* Outh = Kp + ((size_t)(bidx * NH + h) * S_LEN) * HDIM;
            #pragma unroll
            for (int r = 0; r < 4; ++r) {
                int s0 = s_base + 4 * g + r;
                Outh[(size_t)s0 * HDIM + hd]        = f2bf(acc0[r] + bval);
                Outh[(size_t)(s0 + 16) * HDIM + hd] = f2bf(acc1[r] + bval);
            }
        } else {
            short* Vh = Vt + ((size_t)(bidx * NH + h) * HDIM + hd) * S_LEN;
            short4v o0, o1;
            #pragma unroll
            for (int r = 0; r < 4; ++r) { o0[r] = f2bf(acc0[r] + bval); o1[r] = f2bf(acc1[r] + bval); }
            size_t s = s_base + 4 * g;
            *(short4v*)&Vh[s]      = o0;
            *(short4v*)&Vh[s + 16] = o1;
        }
    }
}

// ---------------------------------------------------------------------------
// K2: causal attention: register-only P (swapped QK^T + permuted-k PV, R10,
// verified) + SEQUENTIAL PAIRED q-tiles {63-t, t} so every block does 33-34
// k-tiles regardless of dispatch/CU assignment.  grid 1024 (4 blocks/CU,
// all resident, uniform work).  VGPR ~52, LDS 18.9 KB (comb reused).
// ---------------------------------------------------------------------------
__global__ __launch_bounds__(256) void attn_kernel(
    const short* __restrict__ Qp, const short* __restrict__ Kp,
    const short* __restrict__ Vt, short* __restrict__ Ab)
{
    __shared__ float comb[4][32][36];
    __shared__ float psl[4][2][16];

    const int idx = blockIdx.x;
    const int bh = 4 * (idx & 7) + ((idx >> 3) & 3);   // XCD-local bh groups
    const int t  = idx >> 5;                           // 0..31
    const int b = bh >> 3, hh = bh & 7;
    const int tid = threadIdx.x;
    const int w = tid >> 6, l = tid & 63, g = l >> 4, r15 = l & 15;

    const short* Qph = Qp + (size_t)bh * S_LEN * HDIM;
    const short* Kph = Kp + (size_t)bh * S_LEN * HDIM;
    const short* Vtp = Vt + (size_t)bh * HDIM * S_LEN;
    const f32x4 zero = {};

    #pragma unroll 1
    for (int ph = 0; ph < 2; ++ph) {
        const int q0 = (ph == 0 ? (63 - t) : t) * 32;
        const int ntiles = (q0 + 95) >> 6;

        // Q B-fragments (q rows q0..q0+15 and q0+16..q0+31)
        bf16x8 aq0 = *(const bf16x8*)&Qph[(q0 + r15) * HDIM + 8 * g];
        bf16x8 aq1 = *(const bf16x8*)&Qph[(q0 + 16 + r15) * HDIM + 8 * g];

        f32x4 o00 = {}, o01 = {}, o10 = {}, o11 = {};
        float ps0 = 0.f, ps1 = 0.f;

        const short* kp  = Kph + w * 2048 + r15 * 32 + 8 * g;
        const short* vp0 = Vtp + r15 * S_LEN + w * 64 + 4 * g;
        const short* vp1 = vp0 + 16 * S_LEN;

        for (int kt = w; kt < ntiles; kt += 4, kp += 8192, vp0 += 256, vp1 += 256) {
            const int k0 = kt * 64;
            const bool full = (k0 + 63) <= q0;

            // V loads early: s = k0 + 32ks + {0,16} + 4g..+3, hd = r15 / 16+r15
            short4v v000 = *(const short4v*)(vp0);
            short4v v001 = *(const short4v*)(vp0 + 16);
            short4v v010 = *(const short4v*)(vp1);
            short4v v011 = *(const short4v*)(vp1 + 16);
            short4v v100 = *(const short4v*)(vp0 + 32);
            short4v v101 = *(const short4v*)(vp0 + 48);
            short4v v110 = *(const short4v*)(vp1 + 32);
            short4v v111 = *(const short4v*)(vp1 + 48);

            // Swapped QK^T: lane gets S[q=r15(+16h)][key=k0+16n+4g+r]
            short4v pb[4][2];
            #pragma unroll
            for (int n = 0; n < 4; ++n) {
                bf16x8 ak = *(const bf16x8*)(kp + n * 512);
                __builtin_amdgcn_s_setprio(1);
                f32x4 s0 = __builtin_amdgcn_mfma_f32_16x16x32_bf16(ak, aq0, zero, 0, 0, 0);
                f32x4 s1 = __builtin_amdgcn_mfma_f32_16x16x32_bf16(ak, aq1, zero, 0, 0, 0);
                __builtin_amdgcn_s_setprio(0);
                if (full) {
                    #pragma unroll
                    for (int r = 0; r < 4; ++r) {
                        float e0 = exp2f(s0[r]);
                        float e1 = exp2f(s1[r]);
                        ps0 += e0; ps1 += e1;
                        pb[n][0][r] = f2bf(e0);
                        pb[n][1][r] = f2bf(e1);
                    }
                } else {
                    const int kb = k0 + n * 16 + 4 * g;
                    #pragma unroll
                    for (int r = 0; r < 4; ++r) {
                        int key = kb + r;
                        float e0 = (key <= q0 + r15)      ? exp2f(s0[r]) : 0.0f;
                        float e1 = (key <= q0 + 16 + r15) ? exp2f(s1[r]) : 0.0f;
                        ps0 += e0; ps1 += e1;
                        pb[n][0][r] = f2bf(e0);
                        pb[n][1][r] = f2bf(e1);
                    }
                }
            }

            // PV with permuted k: A-frag = own P regs, B-frag = matching V order
            bf16x8 pa00 = __builtin_shufflevector(pb[0][0], pb[1][0], 0,1,2,3,4,5,6,7);
            bf16x8 pa01 = __builtin_shufflevector(pb[0][1], pb[1][1], 0,1,2,3,4,5,6,7);
            bf16x8 pa10 = __builtin_shufflevector(pb[2][0], pb[3][0], 0,1,2,3,4,5,6,7);
            bf16x8 pa11 = __builtin_shufflevector(pb[2][1], pb[3][1], 0,1,2,3,4,5,6,7);
            bf16x8 bv00 = __builtin_shufflevector(v000, v001, 0,1,2,3,4,5,6,7);
            bf16x8 bv01 = __builtin_shufflevector(v010, v011, 0,1,2,3,4,5,6,7);
            bf16x8 bv10 = __builtin_shufflevector(v100, v101, 0,1,2,3,4,5,6,7);
            bf16x8 bv11 = __builtin_shufflevector(v110, v111, 0,1,2,3,4,5,6,7);

            __builtin_amdgcn_s_setprio(1);
            o00 = __builtin_amdgcn_mfma_f32_16x16x32_bf16(pa00, bv00, o00, 0, 0, 0);
            o01 = __builtin_amdgcn_mfma_f32_16x16x32_bf16(pa00, bv01, o01, 0, 0, 0);
            o10 = __builtin_amdgcn_mfma_f32_16x16x32_bf16(pa01, bv00, o10, 0, 0, 0);
            o11 = __builtin_amdgcn_mfma_f32_16x16x32_bf16(pa01, bv01, o11, 0, 0, 0);
            o00 = __builtin_amdgcn_mfma_f32_16x16x32_bf16(pa10, bv10, o00, 0, 0, 0);
            o01 = __builtin_amdgcn_mfma_f32_16x16x32_bf16(pa10, bv11, o01, 0, 0, 0);
            o10 = __builtin_amdgcn_mfma_f32_16x16x32_bf16(pa11, bv10, o10, 0, 0, 0);
            o11 = __builtin_amdgcn_mfma_f32_16x16x32_bf16(pa11, bv11, o11, 0, 0, 0);
            __builtin_amdgcn_s_setprio(0);
        }

        // rowsum: reduce across the 4 groups (lane ^16, ^32)
        ps0 += __shfl_xor(ps0, 16); ps0 += __shfl_xor(ps0, 32);
        ps1 += __shfl_xor(ps1, 16); ps1 += __shfl_xor(ps1, 32);

        // combine across key-split waves via LDS
        if (l < 16) { psl[w][0][l] = ps0; psl[w][1][l] = ps1; }
        #pragma unroll
        for (int r = 0; r < 4; ++r) {
            comb[w][4 * g + r][r15]           = o00[r];
            comb[w][4 * g + r][16 + r15]      = o01[r];
            comb[w][16 + 4 * g + r][r15]      = o10[r];
            comb[w][16 + 4 * g + r][16 + r15] = o11[r];
        }
        __syncthreads();

        // epilogue: 256 threads cover 32 q-rows x 32 hd (4 each)
        {
            int q = tid >> 3, hd0 = (tid & 7) * 4;
            float ps = psl[0][q >> 4][q & 15] + psl[1][q >> 4][q & 15]
                     + psl[2][q >> 4][q & 15] + psl[3][q >> 4][q & 15];
            float inv = __fdividef(1.0f, ps);
            short4v o;
            #pragma unroll
            for (int j = 0; j < 4; ++j) {
                float v = comb[0][q][hd0 + j] + comb[1][q][hd0 + j]
                        + comb[2][q][hd0 + j] + comb[3][q][hd0 + j];
                o[j] = f2bf(v * inv);
            }
            *(short4v*)&Ab[((size_t)b * S_LEN + q0 + q) * D_MOD + hh * HDIM + hd0] = o;
        }
        if (ph == 0) __syncthreads();   // comb reuse safe for next phase
    }
}

// ---------------------------------------------------------------------------
// K3: output projection, streaming (no LDS).  grid 256.
// ---------------------------------------------------------------------------
__global__ __launch_bounds__(256) void out_proj_kernel(
    const short* __restrict__ Ab, const short* __restrict__ WTo,
    const float* __restrict__ bo, float* __restrict__ out)
{
    const int m0 = blockIdx.x * 32;
    const int tid = threadIdx.x;
    const int w = tid >> 6, l = tid & 63, g = l >> 4, r15 = l & 15;

    bf16x8 af[2][8];
    #pragma unroll
    for (int f = 0; f < 2; ++f)
        #pragma unroll
        for (int kk = 0; kk < 8; ++kk)
            af[f][kk] = *(const bf16x8*)&Ab[(size_t)(m0 + f * 16 + r15) * D_MOD + kk * 32 + 8 * g];

    #pragma unroll
    for (int ntl = 0; ntl < 4; ++ntl) {
        int col = w * 64 + ntl * 16 + r15;
        f32x4 acc0 = {}, acc1 = {};
        #pragma unroll
        for (int kk = 0; kk < 8; ++kk) {
            bf16x8 bfr = *(const bf16x8*)&WTo[(size_t)col * 256 + kk * 32 + 8 * g];
            acc0 = __builtin_amdgcn_mfma_f32_16x16x32_bf16(af[0][kk], bfr, acc0, 0, 0, 0);
            acc1 = __builtin_amdgcn_mfma_f32_16x16x32_bf16(af[1][kk], bfr, acc1, 0, 0, 0);
        }
        float bval = bo[col];
        #pragma unroll
        for (int r = 0; r < 4; ++r) {
            out[(size_t)(m0 + 4 * g + r) * D_MOD + col]      = acc0[r] + bval;
            out[(size_t)(m0 + 16 + 4 * g + r) * D_MOD + col] = acc1[r] + bval;
        }
    }
}

extern "C" void kernel_launch(void* const* d_in, const int* in_sizes, int n_in,
                              void* d_out, int out_size, void* d_ws, size_t ws_size,
                              hipStream_t stream) {
    const float* q_in = (const float*)d_in[0];
    const float* k_in = (const float*)d_in[1];
    const float* v_in = (const float*)d_in[2];
    // d_in[3] = mask: causal tril, applied analytically.
    const float* Wq = (const float*)d_in[4];
    const float* bq = (const float*)d_in[5];
    const float* Wk = (const float*)d_in[6];
    const float* bk = (const float*)d_in[7];
    const float* Wv = (const float*)d_in[8];
    const float* bv = (const float*)d_in[9];
    const float* Wo = (const float*)d_in[10];
    const float* bo = (const float*)d_in[11];
    float* out = (float*)d_out;

    const size_t NTOK = (size_t)BATCH * S_LEN * D_MOD;  // 2M elements
    short* WT = (short*)d_ws;           // 4 x 256 x 256 bf16 = 512 KB
    short* Qp = WT + 4 * 65536;         // packed [bh][s][32], pre-scaled
    short* Kp = Qp + NTOK;              // packed [bh][s][32]
    short* Vt = Kp + NTOK;              // transposed [bh][hd][s]
    short* Ab = Vt + NTOK;              // [b][s][256]

    wtrans_kernel<<<dim3(4, 32), 256, 0, stream>>>(Wq, Wk, Wv, Wo, WT);
    qkv_proj_kernel<<<dim3(256, 3), 256, 0, stream>>>(
        q_in, k_in, v_in, WT, bq, bk, bv, Qp, Kp, Vt);
    attn_kernel<<<1024, 256, 0, stream>>>(Qp, Kp, Vt, Ab);
    out_proj_kernel<<<256, 256, 0, stream>>>(Ab, WT + 3 * 65536, bo, out);
}